// Round 7
// baseline (682.611 us; speedup 1.0000x reference)
//
#include <hip/hip_runtime.h>
#include <hip/hip_cooperative_groups.h>
#include <math.h>
#include <float.h>

namespace cg = cooperative_groups;

#define E_DIM 128
#define GRID_BLKS 512
#define BLK_THREADS 256

typedef unsigned short ushort_t;
typedef __bf16 bf16x8 __attribute__((ext_vector_type(8)));
typedef float  f32x4  __attribute__((ext_vector_type(4)));

struct Params {
    const float *xc_off, *xc_on, *zc_off, *zc_on, *latents, *fake, *Wq, *Wk, *Wv, *Wo;
    const int* ignore;
    int *counts, *cursor, *nearestp, *offsets, *tokens;
    ushort_t *Qpre, *Koff, *Voff, *Kon, *Von, *AO;
    float* out;
    int S, U, B, BS, BU;
};

__device__ inline ushort_t f2bf(float f) {
    union { float f; unsigned int u; } x; x.f = f;
    unsigned int r = x.u + 0x7fffu + ((x.u >> 16) & 1u);   // RNE
    return (ushort_t)(r >> 16);
}
__device__ inline float bf2f(unsigned int hi16) {
    union { unsigned int u; float f; } x; x.u = hi16 << 16;
    return x.f;
}
__device__ inline void lexmin(float& d, int& i, float d2, int i2) {
    if (d2 < d || (d2 == d && i2 < i)) { d = d2; i = i2; }
}

// ---- MFMA tile helpers (64-row x 128-col tile, LDS XOR-swizzled) -----------
__device__ inline void stage_A_f32(char* AsmB, const float* abase, const float* fake,
                                   bool ign, int tid) {
#pragma unroll
    for (int i = 0; i < 8; ++i) {
        int f = (tid + i * 256) * 4;
        int r = f >> 7, c = f & 127;
        float4 v = *(const float4*)(ign ? (fake + c) : (abase + f));
        unsigned int lo = (unsigned int)f2bf(v.x) | ((unsigned int)f2bf(v.y) << 16);
        unsigned int hi = (unsigned int)f2bf(v.z) | ((unsigned int)f2bf(v.w) << 16);
        *(uint2*)(AsmB + r * 256 + ((c * 2) ^ ((r & 7) << 4))) = make_uint2(lo, hi);
    }
}

// W fp32 k-major [128][128] -> bf16 n-major swizzled in LDS (transpose on write)
__device__ inline void stage_W_T(char* WsmB, const float* W, int tid) {
#pragma unroll
    for (int i = 0; i < 16; ++i) {
        int f = (tid + i * 256) * 4;
        int k = f >> 7, n0 = f & 127;
        float4 v = *(const float4*)(W + f);
        float vv[4] = {v.x, v.y, v.z, v.w};
#pragma unroll
        for (int j = 0; j < 4; ++j) {
            int n = n0 + j;
            *(ushort_t*)(WsmB + n * 256 + ((k * 2) ^ ((n & 7) << 4))) = f2bf(vv[j]);
        }
    }
}

__device__ inline void mma_16x128(char* AsmB, char* WsmB, int wv, int lane, f32x4 acc[8]) {
    int l15 = lane & 15, kg = lane >> 4;
    int r = wv * 16 + l15;
#pragma unroll
    for (int kc = 0; kc < 4; ++kc) {
        int kb = (kc * 32 + kg * 8) * 2;
        bf16x8 a = *(const bf16x8*)(AsmB + r * 256 + (kb ^ ((r & 7) << 4)));
#pragma unroll
        for (int nf = 0; nf < 8; ++nf) {
            int n = nf * 16 + l15;
            bf16x8 b = *(const bf16x8*)(WsmB + n * 256 + (kb ^ ((n & 7) << 4)));
            acc[nf] = __builtin_amdgcn_mfma_f32_16x16x32_bf16(a, b, acc[nf], 0, 0, 0);
        }
    }
}

__device__ inline void epi_bf16(ushort_t* C, int row0, int wv, int lane, f32x4 acc[8]) {
    int l15 = lane & 15, kg = lane >> 4;
    int rbase = row0 + wv * 16 + kg * 4;
#pragma unroll
    for (int rr = 0; rr < 4; ++rr) {
        ushort_t* dst = C + (size_t)(rbase + rr) * E_DIM + l15;
#pragma unroll
        for (int nf = 0; nf < 8; ++nf) dst[nf * 16] = f2bf(acc[nf][rr]);
    }
}

__device__ inline void epi_f32(float* C, int row0, int wv, int lane, f32x4 acc[8]) {
    int l15 = lane & 15, kg = lane >> 4;
    int rbase = row0 + wv * 16 + kg * 4;
#pragma unroll
    for (int rr = 0; rr < 4; ++rr) {
        float* dst = C + (size_t)(rbase + rr) * E_DIM + l15;
#pragma unroll
        for (int nf = 0; nf < 8; ++nf) dst[nf * 16] = acc[nf][rr];
    }
}

#define ZERO_ACC(a) do { _Pragma("unroll") for (int _i = 0; _i < 8; ++_i) \
    (a)[_i] = (f32x4){0.f, 0.f, 0.f, 0.f}; } while (0)

// ---- phase 0: zero counts/cursor + all input projections -------------------
__device__ void phase_proj(const Params& p, char* sm, int bid) {
    int tid = threadIdx.x;
    int gid = bid * BLK_THREADS + tid;
    for (int i = gid; i < p.BS; i += GRID_BLKS * BLK_THREADS) {
        p.counts[i] = 0;
        p.cursor[i] = 0;
    }
    char* AsmB = sm;           // 16 KB
    char* WsmB = sm + 16384;   // 32 KB
    int lane = tid & 63, wv = tid >> 6;
    int nQ = p.S / 64, nOff = p.BU / 64, nOn = p.BS / 64;
    int ntask = nQ + nOff + nOn;
    for (int task = bid; task < ntask; task += GRID_BLKS) {
        if (task < nQ) {
            int row0 = task * 64;
            stage_A_f32(AsmB, p.latents + (size_t)row0 * E_DIM, nullptr, false, tid);
            stage_W_T(WsmB, p.Wq, tid);
            __syncthreads();
            f32x4 acc[8]; ZERO_ACC(acc);
            mma_16x128(AsmB, WsmB, wv, lane, acc);
            epi_bf16(p.Qpre, row0, wv, lane, acc);
            __syncthreads();
        } else {
            bool offg = task < nQ + nOff;
            int t = offg ? (task - nQ) : (task - nQ - nOff);
            int row0 = t * 64;
            const float* A = offg ? p.zc_off : p.zc_on;
            bool ign = (!offg) && (*p.ignore != 0);
            ushort_t* C0 = offg ? p.Koff : p.Kon;
            ushort_t* C1 = offg ? p.Voff : p.Von;
            stage_A_f32(AsmB, A + (size_t)row0 * E_DIM, p.fake, ign, tid);
            stage_W_T(WsmB, p.Wk, tid);
            __syncthreads();
            {
                f32x4 acc[8]; ZERO_ACC(acc);
                mma_16x128(AsmB, WsmB, wv, lane, acc);
                epi_bf16(C0, row0, wv, lane, acc);
            }
            __syncthreads();
            stage_W_T(WsmB, p.Wv, tid);   // A tile stays; swap W only
            __syncthreads();
            {
                f32x4 acc[8]; ZERO_ACC(acc);
                mma_16x128(AsmB, WsmB, wv, lane, acc);
                epi_bf16(C1, row0, wv, lane, acc);
            }
            __syncthreads();
        }
    }
}

// ---- phase 1: nearest grid cell (L1 argmin, first-min tie-break) -----------
__device__ void phase_nearest(const Params& p, char* sm, int bid) {
    float4* on = (float4*)sm;                        // 32 KB
    float (*sh_d)[32] = (float(*)[32])(sm + 32768);  // 2 KB
    int   (*sh_i)[32] = (int(*)[32])(sm + 34816);    // 2 KB
    int tpb = p.U / 32;
    int S = p.S, U = p.U;
    for (int task = bid; task < tpb * p.B; task += GRID_BLKS) {
        int b = task / tpb;
        int xt = task - b * tpb;
        const float4* onb = (const float4*)(p.xc_on + (size_t)b * S * 2);
        for (int i = threadIdx.x; i < S / 2; i += BLK_THREADS) on[i] = onb[i];
        __syncthreads();
        int part = threadIdx.x >> 4;
        int ug   = threadIdx.x & 15;
        int u0 = xt * 32 + ug * 2;
        const float2* offb = (const float2*)(p.xc_off + (size_t)b * U * 2);
        float2 pA = offb[u0], pB = offb[u0 + 1];
        int h0 = part * (S / 32), h1 = h0 + (S / 32);
        float dA0 = FLT_MAX, dA1 = FLT_MAX, dB0 = FLT_MAX, dB1 = FLT_MAX;
        int iA0 = 0, iA1 = 0, iB0 = 0, iB1 = 0;
        for (int h = h0; h < h1; ++h) {
            float4 cc = on[h];
            int s = h * 2;
            float a0 = fabsf(pA.x - cc.x) + fabsf(pA.y - cc.y);
            float a1 = fabsf(pA.x - cc.z) + fabsf(pA.y - cc.w);
            float b0 = fabsf(pB.x - cc.x) + fabsf(pB.y - cc.y);
            float b1 = fabsf(pB.x - cc.z) + fabsf(pB.y - cc.w);
            if (a0 < dA0) { dA0 = a0; iA0 = s; }
            if (a1 < dA1) { dA1 = a1; iA1 = s + 1; }
            if (b0 < dB0) { dB0 = b0; iB0 = s; }
            if (b1 < dB1) { dB1 = b1; iB1 = s + 1; }
        }
        lexmin(dA0, iA0, dA1, iA1);
        lexmin(dB0, iB0, dB1, iB1);
        sh_d[part][ug * 2] = dA0;     sh_i[part][ug * 2] = iA0;
        sh_d[part][ug * 2 + 1] = dB0; sh_i[part][ug * 2 + 1] = iB0;
        __syncthreads();
        if (threadIdx.x < 32) {
            int ul = threadIdx.x;
            float d = sh_d[0][ul]; int i = sh_i[0][ul];
#pragma unroll
            for (int pp = 1; pp < 16; ++pp) lexmin(d, i, sh_d[pp][ul], sh_i[pp][ul]);
            int u = xt * 32 + ul;
            p.nearestp[b * U + u] = i;
            atomicAdd(&p.counts[b * S + i], 1);
        }
        __syncthreads();
    }
}

// ---- phase 2: exclusive scan (block 0 only; 2-pass streaming) --------------
__device__ void phase_scan(const Params& p, char* smraw) {
    int* part = (int*)smraw;
    int tid = threadIdx.x;
    int N = p.BS;
    int items = N / BLK_THREADS;
    int base = tid * items;
    int sum = 0;
    for (int i = 0; i < items; ++i) sum += p.counts[base + i];
    part[tid] = sum;
    __syncthreads();
    for (int off = 1; off < BLK_THREADS; off <<= 1) {
        int v = (tid >= off) ? part[tid - off] : 0;
        __syncthreads();
        part[tid] += v;
        __syncthreads();
    }
    int run = (tid == 0) ? 0 : part[tid - 1];
    for (int i = 0; i < items; ++i) {
        p.offsets[base + i] = run;
        run += p.counts[base + i];
    }
    if (tid == BLK_THREADS - 1) p.offsets[N] = run;
}

// ---- phase 3: fill CSR token lists -----------------------------------------
__device__ void phase_fill(const Params& p, int bid) {
    int gid = bid * BLK_THREADS + threadIdx.x;
    for (int i = gid; i < p.BU; i += GRID_BLKS * BLK_THREADS) {
        int b = i / p.U;
        int u = i - b * p.U;
        int c = b * p.S + p.nearestp[i];
        int pos = p.offsets[c] + atomicAdd(&p.cursor[c], 1);
        p.tokens[pos] = u;
    }
}

// ---- phase 4: per-cell masked MHA (1 wave per cell, online softmax) --------
__device__ void phase_attn(const Params& p, int bid) {
    int wv = threadIdx.x >> 6;
    int lane = threadIdx.x & 63;
    for (int c = bid * 4 + wv; c < p.BS; c += GRID_BLKS * 4) {
        int b = c / p.S;
        int cl = c - b * p.S;
        unsigned int qw = ((const unsigned int*)(p.Qpre + (size_t)cl * E_DIM))[lane];
        float q0 = bf2f(qw & 0xffffu) * 0.25f;   // 1/sqrt(dh) folded in
        float q1 = bf2f(qw >> 16) * 0.25f;
        unsigned int kw = ((const unsigned int*)(p.Kon + (size_t)c * E_DIM))[lane];
        float pp = q0 * bf2f(kw & 0xffffu) + q1 * bf2f(kw >> 16);
        pp += __shfl_xor(pp, 4, 8);
        pp += __shfl_xor(pp, 2, 8);
        pp += __shfl_xor(pp, 1, 8);
        unsigned int vw = ((const unsigned int*)(p.Von + (size_t)c * E_DIM))[lane];
        float mm = pp, ll = 1.f;
        float o0 = bf2f(vw & 0xffffu), o1 = bf2f(vw >> 16);
        int beg = p.offsets[c], end = p.offsets[c + 1];
        for (int t = beg; t < end; ++t) {
            int u = p.tokens[t];
            size_t rr = ((size_t)b * p.U + u) * E_DIM;
            unsigned int kw2 = ((const unsigned int*)(p.Koff + rr))[lane];
            unsigned int vw2 = ((const unsigned int*)(p.Voff + rr))[lane];
            float p2 = q0 * bf2f(kw2 & 0xffffu) + q1 * bf2f(kw2 >> 16);
            p2 += __shfl_xor(p2, 4, 8);
            p2 += __shfl_xor(p2, 2, 8);
            p2 += __shfl_xor(p2, 1, 8);
            float v0 = bf2f(vw2 & 0xffffu), v1 = bf2f(vw2 >> 16);
            float nm = fmaxf(mm, p2);
            float f = __expf(mm - nm), w = __expf(p2 - nm);
            ll = ll * f + w;
            o0 = o0 * f + w * v0;
            o1 = o1 * f + w * v1;
            mm = nm;
        }
        float inv = 1.f / ll;
        ((unsigned int*)(p.AO + (size_t)c * E_DIM))[lane] =
            (unsigned int)f2bf(o0 * inv) | ((unsigned int)f2bf(o1 * inv) << 16);
    }
}

// ---- phase 5: output projection AO @ Wo -> out (fp32) ----------------------
__device__ void phase_gemmO(const Params& p, char* sm, int bid) {
    char* AsmB = sm;
    char* WsmB = sm + 16384;
    int tid = threadIdx.x, lane = tid & 63, wv = tid >> 6;
    for (int tile = bid; tile < p.BS / 64; tile += GRID_BLKS) {
        int row0 = tile * 64;
        const char* abase = (const char*)(p.AO + (size_t)row0 * E_DIM);
#pragma unroll
        for (int i = 0; i < 4; ++i) {
            int gb = (tid + i * 256) * 16;
            int r = gb >> 8, cb = gb & 255;
            uint4 v = *(const uint4*)(abase + gb);
            *(uint4*)(AsmB + r * 256 + (cb ^ ((r & 7) << 4))) = v;
        }
        stage_W_T(WsmB, p.Wo, tid);
        __syncthreads();
        f32x4 acc[8]; ZERO_ACC(acc);
        mma_16x128(AsmB, WsmB, wv, lane, acc);
        epi_f32(p.out, row0, wv, lane, acc);
        __syncthreads();
    }
}

// ---------------------------------------------------------------------------
__global__ __launch_bounds__(BLK_THREADS) void mega_kernel(Params p, int only) {
    __shared__ __align__(16) char sm[49152];   // 48 KB -> 3 blocks/CU >= 2 needed
    int bid = blockIdx.x;
    bool all = (only < 0);
    if (all || only == 0) phase_proj(p, sm, bid);
    if (all) { __threadfence(); cg::this_grid().sync(); }
    if (all || only == 1) phase_nearest(p, sm, bid);
    if (all) { __threadfence(); cg::this_grid().sync(); }
    if (all || only == 2) { if (bid == 0) phase_scan(p, sm); }
    if (all) { __threadfence(); cg::this_grid().sync(); }
    if (all || only == 3) phase_fill(p, bid);
    if (all) { __threadfence(); cg::this_grid().sync(); }
    if (all || only == 4) phase_attn(p, bid);
    if (all) { __threadfence(); cg::this_grid().sync(); }
    if (all || only == 5) phase_gemmO(p, sm, bid);
}

// ---------------------------------------------------------------------------
extern "C" void kernel_launch(void* const* d_in, const int* in_sizes, int n_in,
                              void* d_out, int out_size, void* d_ws, size_t ws_size,
                              hipStream_t stream) {
    const int E = in_sizes[5];              // 128
    const int S = in_sizes[4] / E;          // 4096
    const int B = in_sizes[1] / (S * 2);    // 4
    const int U = in_sizes[0] / (B * 2);    // 4096
    const int BS = B * S, BU = B * U;

    char* ws = (char*)d_ws;
    size_t off = 0;
    auto alloc = [&](size_t bytes) {
        size_t r = off;
        off += (bytes + 255) & ~(size_t)255;
        return r;
    };
    Params p;
    p.xc_off  = (const float*)d_in[0];
    p.xc_on   = (const float*)d_in[1];
    p.zc_off  = (const float*)d_in[2];
    p.zc_on   = (const float*)d_in[3];
    p.latents = (const float*)d_in[4];
    p.fake    = (const float*)d_in[5];
    p.Wq      = (const float*)d_in[6];
    p.Wk      = (const float*)d_in[7];
    p.Wv      = (const float*)d_in[8];
    p.Wo      = (const float*)d_in[9];
    p.ignore  = (const int*)d_in[10];
    p.counts  = (int*)(ws + alloc((size_t)BS * 4));
    p.cursor  = (int*)(ws + alloc((size_t)BS * 4));
    p.nearestp= (int*)(ws + alloc((size_t)BU * 4));
    p.offsets = (int*)(ws + alloc((size_t)(BS + 1) * 4));
    p.tokens  = (int*)(ws + alloc((size_t)BU * 4));
    p.Qpre    = (ushort_t*)(ws + alloc((size_t)S * E * 2));
    p.Koff    = (ushort_t*)(ws + alloc((size_t)BU * E * 2));
    p.Voff    = (ushort_t*)(ws + alloc((size_t)BU * E * 2));
    p.Kon     = (ushort_t*)(ws + alloc((size_t)BS * E * 2));
    p.Von     = (ushort_t*)(ws + alloc((size_t)BS * E * 2));
    p.AO      = (ushort_t*)(ws + alloc((size_t)BS * E * 2));
    p.out     = (float*)d_out;
    p.S = S; p.U = U; p.B = B; p.BS = BS; p.BU = BU;

    int only = -1;
    void* args[] = { (void*)&p, (void*)&only };
    hipError_t err = hipLaunchCooperativeKernel((const void*)mega_kernel,
                                                dim3(GRID_BLKS), dim3(BLK_THREADS),
                                                args, 0, stream);
    if (err != hipSuccess) {
        // fallback: same phases as separate launches (identical semantics)
        for (int ph = 0; ph < 6; ++ph)
            mega_kernel<<<GRID_BLKS, BLK_THREADS, 0, stream>>>(p, ph);
    }
}

// Round 8
// 182.043 us; speedup vs baseline: 3.7497x; 3.7497x over previous
//
#include <hip/hip_runtime.h>
#include <math.h>
#include <float.h>

#define E_DIM 128
typedef unsigned short ushort_t;
typedef __bf16 bf16x8 __attribute__((ext_vector_type(8)));
typedef float  f32x4  __attribute__((ext_vector_type(4)));

__device__ inline ushort_t f2bf(float f) {
    union { float f; unsigned int u; } x; x.f = f;
    unsigned int r = x.u + 0x7fffu + ((x.u >> 16) & 1u);   // RNE
    return (ushort_t)(r >> 16);
}
__device__ inline float bf2f(unsigned int hi16) {
    union { unsigned int u; float f; } x; x.u = hi16 << 16;
    return x.f;
}
__device__ inline void lexmin(float& d, int& i, float d2, int i2) {
    if (d2 < d || (d2 == d && i2 < i)) { d = d2; i = i2; }
}

// ---- MFMA tile helpers (64 rows x 128 cols, 4 waves, LDS XOR-swizzled) ----
__device__ inline void stage_A_f32(char* AsmB, const float* abase, const float* fake,
                                   bool ign, int tid) {
#pragma unroll
    for (int i = 0; i < 8; ++i) {
        int f = (tid + i * 256) * 4;
        int r = f >> 7, c = f & 127;
        float4 v = *(const float4*)(ign ? (fake + c) : (abase + f));
        unsigned int lo = (unsigned int)f2bf(v.x) | ((unsigned int)f2bf(v.y) << 16);
        unsigned int hi = (unsigned int)f2bf(v.z) | ((unsigned int)f2bf(v.w) << 16);
        *(uint2*)(AsmB + r * 256 + ((c * 2) ^ ((r & 7) << 4))) = make_uint2(lo, hi);
    }
}

// stage pre-transposed bf16 W (n-major [128][128]) -> swizzled LDS, uint4, conflict-free
__device__ inline void stage_WT(char* WsmB, const ushort_t* Wt, int tid) {
#pragma unroll
    for (int i = 0; i < 8; ++i) {
        int gb = (tid + i * 256) * 16;
        int n = gb >> 8, cb = gb & 255;
        uint4 v = *(const uint4*)((const char*)Wt + gb);
        *(uint4*)(WsmB + n * 256 + (cb ^ ((n & 7) << 4))) = v;
    }
}

__device__ inline void mma_16x128(char* AsmB, char* WsmB, int wv, int lane, f32x4 acc[8]) {
    int l15 = lane & 15, kg = lane >> 4;
    int r = wv * 16 + l15;
#pragma unroll
    for (int kc = 0; kc < 4; ++kc) {
        int kb = (kc * 32 + kg * 8) * 2;
        bf16x8 a = *(const bf16x8*)(AsmB + r * 256 + (kb ^ ((r & 7) << 4)));
#pragma unroll
        for (int nf = 0; nf < 8; ++nf) {
            int n = nf * 16 + l15;
            bf16x8 b = *(const bf16x8*)(WsmB + n * 256 + (kb ^ ((n & 7) << 4)));
            acc[nf] = __builtin_amdgcn_mfma_f32_16x16x32_bf16(a, b, acc[nf], 0, 0, 0);
        }
    }
}

__device__ inline void mma_16x128_dual(char* AsmB, char* Wsm0B, char* Wsm1B,
                                       int wv, int lane, f32x4 acc0[8], f32x4 acc1[8]) {
    int l15 = lane & 15, kg = lane >> 4;
    int r = wv * 16 + l15;
#pragma unroll
    for (int kc = 0; kc < 4; ++kc) {
        int kb = (kc * 32 + kg * 8) * 2;
        bf16x8 a = *(const bf16x8*)(AsmB + r * 256 + (kb ^ ((r & 7) << 4)));
#pragma unroll
        for (int nf = 0; nf < 8; ++nf) {
            int n = nf * 16 + l15;
            int nb = (kb ^ ((n & 7) << 4));
            bf16x8 b0 = *(const bf16x8*)(Wsm0B + n * 256 + nb);
            acc0[nf] = __builtin_amdgcn_mfma_f32_16x16x32_bf16(a, b0, acc0[nf], 0, 0, 0);
            bf16x8 b1 = *(const bf16x8*)(Wsm1B + n * 256 + nb);
            acc1[nf] = __builtin_amdgcn_mfma_f32_16x16x32_bf16(a, b1, acc1[nf], 0, 0, 0);
        }
    }
}

__device__ inline void epi_bf16(ushort_t* C, int row0, int wv, int lane, f32x4 acc[8]) {
    int l15 = lane & 15, kg = lane >> 4;
    int rbase = row0 + wv * 16 + kg * 4;
#pragma unroll
    for (int rr = 0; rr < 4; ++rr) {
        ushort_t* dst = C + (size_t)(rbase + rr) * E_DIM + l15;
#pragma unroll
        for (int nf = 0; nf < 8; ++nf) dst[nf * 16] = f2bf(acc[nf][rr]);
    }
}

__device__ inline void epi_f32(float* C, int row0, int wv, int lane, f32x4 acc[8]) {
    int l15 = lane & 15, kg = lane >> 4;
    int rbase = row0 + wv * 16 + kg * 4;
#pragma unroll
    for (int rr = 0; rr < 4; ++rr) {
        float* dst = C + (size_t)(rbase + rr) * E_DIM + l15;
#pragma unroll
        for (int nf = 0; nf < 8; ++nf) dst[nf * 16] = acc[nf][rr];
    }
}

#define ZERO_ACC(a) do { _Pragma("unroll") for (int _i = 0; _i < 8; ++_i) \
    (a)[_i] = (f32x4){0.f, 0.f, 0.f, 0.f}; } while (0)

// ---------------------------------------------------------------------------
// K1: blocks [0, NB): nearest (L1 argmin, first-min tie-break)
//     blocks [NB, NB+64): fp32->bf16 n-major weight transpose (coalesced reads)
// ---------------------------------------------------------------------------
__global__ __launch_bounds__(256) void pre_kernel(
        const float* __restrict__ xc_off, const float* __restrict__ xc_on,
        const float* __restrict__ Wq, const float* __restrict__ Wk,
        const float* __restrict__ Wv, const float* __restrict__ Wo,
        ushort_t* __restrict__ WT, int* __restrict__ nearest, int U, int S, int B) {
    __shared__ __align__(16) char smraw[36928];
    const int NB = (U / 32) * B;
    int bid = blockIdx.x;
    int tid = threadIdx.x;
    if (bid >= NB) {
        int base = (bid - NB) * 1024 + tid;
#pragma unroll
        for (int j = 0; j < 4; ++j) {
            int idx = base + j * 256;
            int w = idx >> 14;
            int rem = idx & 16383;
            int k = rem >> 7, n = rem & 127;
            const float* src = (w == 0) ? Wq : (w == 1) ? Wk : (w == 2) ? Wv : Wo;
            WT[(size_t)w * 16384 + n * E_DIM + k] = f2bf(src[k * E_DIM + n]);
        }
        return;
    }
    float4* on = (float4*)smraw;                          // 32 KB
    float (*sh_d)[32] = (float(*)[32])(smraw + 32768);    // 2 KB
    int   (*sh_i)[32] = (int(*)[32])(smraw + 34816);      // 2 KB
    int tpb = U / 32;
    int b = bid / tpb;
    int xt = bid - b * tpb;
    const float4* onb = (const float4*)(xc_on + (size_t)b * S * 2);
    for (int i = tid; i < S / 2; i += 256) on[i] = onb[i];
    __syncthreads();
    int part = tid >> 4;
    int ug   = tid & 15;
    int u0 = xt * 32 + ug * 2;
    const float2* offb = (const float2*)(xc_off + (size_t)b * U * 2);
    float2 pA = offb[u0], pB = offb[u0 + 1];
    int h0 = part * (S / 32), h1 = h0 + (S / 32);
    float dA0 = FLT_MAX, dA1 = FLT_MAX, dB0 = FLT_MAX, dB1 = FLT_MAX;
    int iA0 = 0, iA1 = 0, iB0 = 0, iB1 = 0;
    for (int h = h0; h < h1; ++h) {
        float4 cc = on[h];
        int s = h * 2;
        float a0 = fabsf(pA.x - cc.x) + fabsf(pA.y - cc.y);
        float a1 = fabsf(pA.x - cc.z) + fabsf(pA.y - cc.w);
        float b0 = fabsf(pB.x - cc.x) + fabsf(pB.y - cc.y);
        float b1 = fabsf(pB.x - cc.z) + fabsf(pB.y - cc.w);
        if (a0 < dA0) { dA0 = a0; iA0 = s; }
        if (a1 < dA1) { dA1 = a1; iA1 = s + 1; }
        if (b0 < dB0) { dB0 = b0; iB0 = s; }
        if (b1 < dB1) { dB1 = b1; iB1 = s + 1; }
    }
    lexmin(dA0, iA0, dA1, iA1);
    lexmin(dB0, iB0, dB1, iB1);
    sh_d[part][ug * 2] = dA0;     sh_i[part][ug * 2] = iA0;
    sh_d[part][ug * 2 + 1] = dB0; sh_i[part][ug * 2 + 1] = iB0;
    __syncthreads();
    if (tid < 32) {
        float d = sh_d[0][tid]; int i = sh_i[0][tid];
#pragma unroll
        for (int pp = 1; pp < 16; ++pp) lexmin(d, i, sh_d[pp][tid], sh_i[pp][tid]);
        nearest[b * U + xt * 32 + tid] = i;
    }
}

// ---------------------------------------------------------------------------
// K2: block 0 = CSR build (counts in LDS via atomics + scan + fill; no memset,
//     no global cursor); blocks 1..576 = MFMA projection tiles.
// ---------------------------------------------------------------------------
__global__ __launch_bounds__(256) void proj_csr_kernel(
        const float* __restrict__ latents, const float* __restrict__ zc_off,
        const float* __restrict__ zc_on, const float* __restrict__ fake,
        const int* __restrict__ ignore, const ushort_t* __restrict__ WT,
        ushort_t* __restrict__ Qpre, ushort_t* __restrict__ Koff,
        ushort_t* __restrict__ Voff, ushort_t* __restrict__ Kon,
        ushort_t* __restrict__ Von,
        const int* __restrict__ nearest, int* __restrict__ offsets,
        int* __restrict__ tokens, int S, int U, int B) {
    __shared__ __align__(16) char sm[81920];   // 80 KB -> 2 blocks/CU
    const int BS = B * S, BU = B * U;
    const int tid = threadIdx.x;

    if (blockIdx.x == 0) {
        // ---- CSR: count -> scan -> fill, all in one block ----
        int* cnt = (int*)sm;                   // 64 KB (BS ints)
        int* part = (int*)(sm + 65536);        // 1 KB
        for (int i = tid; i < BS; i += 256) cnt[i] = 0;
        __syncthreads();
        for (int i = tid; i < BU; i += 256) {
            int b = i / U;
            atomicAdd(&cnt[b * S + nearest[i]], 1);
        }
        __syncthreads();
        const int items = BS / 256;            // 64
        int base = tid * items;
        int sum = 0;
        for (int i = 0; i < items; ++i) sum += cnt[base + i];
        part[tid] = sum;
        __syncthreads();
        for (int off = 1; off < 256; off <<= 1) {
            int v = (tid >= off) ? part[tid - off] : 0;
            __syncthreads();
            part[tid] += v;
            __syncthreads();
        }
        int run = (tid == 0) ? 0 : part[tid - 1];
        for (int i = 0; i < items; ++i) {
            int c = cnt[base + i];
            offsets[base + i] = run;
            cnt[base + i] = run;               // becomes the cursor
            run += c;
        }
        if (tid == 255) offsets[BS] = run;
        __syncthreads();
        for (int i = tid; i < BU; i += 256) {
            int b = i / U;
            int u = i - b * U;
            int c = b * S + nearest[i];
            int pos = atomicAdd(&cnt[c], 1);
            tokens[pos] = u;
        }
        return;
    }

    // ---- projection tiles ----
    char* AsmB  = sm;            // 16 KB
    char* Wsm0B = sm + 16384;    // 32 KB
    char* Wsm1B = sm + 49152;    // 32 KB
    const int lane = tid & 63, wv = tid >> 6;
    const int nQ = S / 64, nOff = BU / 64;
    int t = blockIdx.x - 1;
    const ushort_t* WqT = WT;
    const ushort_t* WkT = WT + 16384;
    const ushort_t* WvT = WT + 32768;

    if (t < nQ) {
        int row0 = t * 64;
        stage_A_f32(AsmB, latents + (size_t)row0 * E_DIM, nullptr, false, tid);
        stage_WT(Wsm0B, WqT, tid);
        __syncthreads();
        f32x4 acc[8]; ZERO_ACC(acc);
        mma_16x128(AsmB, Wsm0B, wv, lane, acc);
        epi_bf16(Qpre, row0, wv, lane, acc);
        return;
    }
    bool offg = (t < nQ + nOff);
    int tt = offg ? (t - nQ) : (t - nQ - nOff);
    int row0 = tt * 64;
    const float* A = offg ? zc_off : zc_on;
    bool ign = (!offg) && (*ignore != 0);
    ushort_t* C0 = offg ? Koff : Kon;
    ushort_t* C1 = offg ? Voff : Von;
    stage_A_f32(AsmB, A + (size_t)row0 * E_DIM, fake, ign, tid);
    stage_WT(Wsm0B, WkT, tid);
    stage_WT(Wsm1B, WvT, tid);
    __syncthreads();
    f32x4 acc0[8], acc1[8]; ZERO_ACC(acc0); ZERO_ACC(acc1);
    mma_16x128_dual(AsmB, Wsm0B, Wsm1B, wv, lane, acc0, acc1);
    epi_bf16(C0, row0, wv, lane, acc0);
    epi_bf16(C1, row0, wv, lane, acc1);
}

// ---------------------------------------------------------------------------
// K3: per-cell masked MHA (1 wave per cell, online softmax, bf16 K/V)
// ---------------------------------------------------------------------------
__global__ __launch_bounds__(256) void attn_kernel(
        const ushort_t* __restrict__ Qpre,
        const ushort_t* __restrict__ Koff, const ushort_t* __restrict__ Voff,
        const ushort_t* __restrict__ Kon, const ushort_t* __restrict__ Von,
        const int* __restrict__ offsets, const int* __restrict__ tokens,
        ushort_t* __restrict__ AO, int S, int U) {
    int wv = threadIdx.x >> 6;
    int lane = threadIdx.x & 63;
    int c = blockIdx.x * 4 + wv;
    int b = c / S;
    int cl = c - b * S;

    unsigned int qw = ((const unsigned int*)(Qpre + (size_t)cl * E_DIM))[lane];
    float q0 = bf2f(qw & 0xffffu) * 0.25f;   // 1/sqrt(dh) folded in
    float q1 = bf2f(qw >> 16) * 0.25f;

    unsigned int kw = ((const unsigned int*)(Kon + (size_t)c * E_DIM))[lane];
    float pp = q0 * bf2f(kw & 0xffffu) + q1 * bf2f(kw >> 16);
    pp += __shfl_xor(pp, 4, 8);
    pp += __shfl_xor(pp, 2, 8);
    pp += __shfl_xor(pp, 1, 8);
    unsigned int vw = ((const unsigned int*)(Von + (size_t)c * E_DIM))[lane];
    float mm = pp, ll = 1.f;
    float o0 = bf2f(vw & 0xffffu), o1 = bf2f(vw >> 16);

    int beg = offsets[c], end = offsets[c + 1];
    for (int t = beg; t < end; ++t) {
        int u = tokens[t];
        size_t rr = ((size_t)b * U + u) * E_DIM;
        unsigned int kw2 = ((const unsigned int*)(Koff + rr))[lane];
        unsigned int vw2 = ((const unsigned int*)(Voff + rr))[lane];
        float p2 = q0 * bf2f(kw2 & 0xffffu) + q1 * bf2f(kw2 >> 16);
        p2 += __shfl_xor(p2, 4, 8);
        p2 += __shfl_xor(p2, 2, 8);
        p2 += __shfl_xor(p2, 1, 8);
        float v0 = bf2f(vw2 & 0xffffu), v1 = bf2f(vw2 >> 16);
        float nm = fmaxf(mm, p2);
        float f = __expf(mm - nm), w = __expf(p2 - nm);
        ll = ll * f + w;
        o0 = o0 * f + w * v0;
        o1 = o1 * f + w * v1;
        mm = nm;
    }
    float inv = 1.f / ll;
    ((unsigned int*)(AO + (size_t)c * E_DIM))[lane] =
        (unsigned int)f2bf(o0 * inv) | ((unsigned int)f2bf(o1 * inv) << 16);
}

// ---------------------------------------------------------------------------
// K4: output projection AO(bf16) @ Wo -> out (fp32)
// ---------------------------------------------------------------------------
__global__ __launch_bounds__(256) void gemmO_kernel(
        const ushort_t* __restrict__ AO, const ushort_t* __restrict__ WoT,
        float* __restrict__ out, int BS) {
    __shared__ __align__(16) char sm[49152];
    char* AsmB = sm;
    char* WsmB = sm + 16384;
    int tid = threadIdx.x, lane = tid & 63, wv = tid >> 6;
    int row0 = blockIdx.x * 64;
    const char* abase = (const char*)(AO + (size_t)row0 * E_DIM);
#pragma unroll
    for (int i = 0; i < 4; ++i) {
        int gb = (tid + i * 256) * 16;
        int r = gb >> 8, cb = gb & 255;
        uint4 v = *(const uint4*)(abase + gb);
        *(uint4*)(AsmB + r * 256 + (cb ^ ((r & 7) << 4))) = v;
    }
    stage_WT(WsmB, WoT, tid);
    __syncthreads();
    f32x4 acc[8]; ZERO_ACC(acc);
    mma_16x128(AsmB, WsmB, wv, lane, acc);
    epi_f32(out, row0, wv, lane, acc);
}

// ---------------------------------------------------------------------------
extern "C" void kernel_launch(void* const* d_in, const int* in_sizes, int n_in,
                              void* d_out, int out_size, void* d_ws, size_t ws_size,
                              hipStream_t stream) {
    const float* xc_off  = (const float*)d_in[0];
    const float* xc_on   = (const float*)d_in[1];
    const float* zc_off  = (const float*)d_in[2];
    const float* zc_on   = (const float*)d_in[3];
    const float* latents = (const float*)d_in[4];
    const float* fake    = (const float*)d_in[5];
    const float* Wq      = (const float*)d_in[6];
    const float* Wk      = (const float*)d_in[7];
    const float* Wv      = (const float*)d_in[8];
    const float* Wo      = (const float*)d_in[9];
    const int*   ignore  = (const int*)d_in[10];

    const int E = in_sizes[5];              // 128
    const int S = in_sizes[4] / E;          // 4096
    const int B = in_sizes[1] / (S * 2);    // 4
    const int U = in_sizes[0] / (B * 2);    // 4096
    const int BS = B * S, BU = B * U;

    char* ws = (char*)d_ws;
    size_t off = 0;
    auto alloc = [&](size_t bytes) {
        size_t r = off;
        off += (bytes + 255) & ~(size_t)255;
        return r;
    };
    ushort_t* WT      = (ushort_t*)(ws + alloc((size_t)4 * E * E * 2));
    int*      nearest = (int*)(ws + alloc((size_t)BU * 4));
    int*      offsets = (int*)(ws + alloc((size_t)(BS + 1) * 4));
    int*      tokens  = (int*)(ws + alloc((size_t)BU * 4));
    ushort_t* Qpre    = (ushort_t*)(ws + alloc((size_t)S * E * 2));
    ushort_t* Koff    = (ushort_t*)(ws + alloc((size_t)BU * E * 2));
    ushort_t* Voff    = (ushort_t*)(ws + alloc((size_t)BU * E * 2));
    ushort_t* Kon     = (ushort_t*)(ws + alloc((size_t)BS * E * 2));
    ushort_t* Von     = (ushort_t*)(ws + alloc((size_t)BS * E * 2));
    ushort_t* AO      = (ushort_t*)(ws + alloc((size_t)BS * E * 2));

    const int NB = (U / 32) * B;            // 512 nearest blocks
    pre_kernel<<<NB + 64, 256, 0, stream>>>(xc_off, xc_on, Wq, Wk, Wv, Wo,
                                            WT, nearest, U, S, B);

    const int ntile = S / 64 + BU / 64 + BS / 64;   // 576
    proj_csr_kernel<<<ntile + 1, 256, 0, stream>>>(latents, zc_off, zc_on, fake, ignore,
                                                   WT, Qpre, Koff, Voff, Kon, Von,
                                                   nearest, offsets, tokens, S, U, B);

    attn_kernel<<<BS / 4, 256, 0, stream>>>(Qpre, Koff, Voff, Kon, Von,
                                            offsets, tokens, AO, S, U);

    gemmO_kernel<<<BS / 64, 256, 0, stream>>>(AO, WT + 3 * E * E, (float*)d_out, BS);
}

// Round 9
// 136.391 us; speedup vs baseline: 5.0048x; 1.3347x over previous
//
#include <hip/hip_runtime.h>
#include <math.h>
#include <float.h>

#define E_DIM 128
typedef unsigned short ushort_t;
typedef __bf16 bf16x8 __attribute__((ext_vector_type(8)));
typedef float  f32x4  __attribute__((ext_vector_type(4)));

__device__ inline ushort_t f2bf(float f) {
    union { float f; unsigned int u; } x; x.f = f;
    unsigned int r = x.u + 0x7fffu + ((x.u >> 16) & 1u);   // RNE
    return (ushort_t)(r >> 16);
}
__device__ inline float bf2f(unsigned int hi16) {
    union { unsigned int u; float f; } x; x.u = hi16 << 16;
    return x.f;
}
__device__ inline void lexmin(float& d, int& i, float d2, int i2) {
    if (d2 < d || (d2 == d && i2 < i)) { d = d2; i = i2; }
}

// ---- MFMA tile helpers (64 rows x 128 cols, 4 waves, LDS XOR-swizzled) ----
__device__ inline void stage_A_f32(char* AsmB, const float* abase, const float* fake,
                                   bool ign, int tid) {
#pragma unroll
    for (int i = 0; i < 8; ++i) {
        int f = (tid + i * 256) * 4;
        int r = f >> 7, c = f & 127;
        float4 v = *(const float4*)(ign ? (fake + c) : (abase + f));
        unsigned int lo = (unsigned int)f2bf(v.x) | ((unsigned int)f2bf(v.y) << 16);
        unsigned int hi = (unsigned int)f2bf(v.z) | ((unsigned int)f2bf(v.w) << 16);
        *(uint2*)(AsmB + r * 256 + ((c * 2) ^ ((r & 7) << 4))) = make_uint2(lo, hi);
    }
}

// stage pre-transposed bf16 W (n-major [128][128]) -> swizzled LDS, uint4
__device__ inline void stage_WT(char* WsmB, const ushort_t* Wt, int tid) {
#pragma unroll
    for (int i = 0; i < 8; ++i) {
        int gb = (tid + i * 256) * 16;
        int n = gb >> 8, cb = gb & 255;
        uint4 v = *(const uint4*)((const char*)Wt + gb);
        *(uint4*)(WsmB + n * 256 + (cb ^ ((n & 7) << 4))) = v;
    }
}

__device__ inline void mma_16x128(char* AsmB, char* WsmB, int wv, int lane, f32x4 acc[8]) {
    int l15 = lane & 15, kg = lane >> 4;
    int r = wv * 16 + l15;
#pragma unroll
    for (int kc = 0; kc < 4; ++kc) {
        int kb = (kc * 32 + kg * 8) * 2;
        bf16x8 a = *(const bf16x8*)(AsmB + r * 256 + (kb ^ ((r & 7) << 4)));
#pragma unroll
        for (int nf = 0; nf < 8; ++nf) {
            int n = nf * 16 + l15;
            bf16x8 b = *(const bf16x8*)(WsmB + n * 256 + (kb ^ ((n & 7) << 4)));
            acc[nf] = __builtin_amdgcn_mfma_f32_16x16x32_bf16(a, b, acc[nf], 0, 0, 0);
        }
    }
}

__device__ inline void mma_16x128_dual(char* AsmB, char* Wsm0B, char* Wsm1B,
                                       int wv, int lane, f32x4 acc0[8], f32x4 acc1[8]) {
    int l15 = lane & 15, kg = lane >> 4;
    int r = wv * 16 + l15;
#pragma unroll
    for (int kc = 0; kc < 4; ++kc) {
        int kb = (kc * 32 + kg * 8) * 2;
        bf16x8 a = *(const bf16x8*)(AsmB + r * 256 + (kb ^ ((r & 7) << 4)));
#pragma unroll
        for (int nf = 0; nf < 8; ++nf) {
            int n = nf * 16 + l15;
            int nb = (kb ^ ((n & 7) << 4));
            bf16x8 b0 = *(const bf16x8*)(Wsm0B + n * 256 + nb);
            acc0[nf] = __builtin_amdgcn_mfma_f32_16x16x32_bf16(a, b0, acc0[nf], 0, 0, 0);
            bf16x8 b1 = *(const bf16x8*)(Wsm1B + n * 256 + nb);
            acc1[nf] = __builtin_amdgcn_mfma_f32_16x16x32_bf16(a, b1, acc1[nf], 0, 0, 0);
        }
    }
}

__device__ inline void epi_bf16(ushort_t* C, int row0, int wv, int lane, f32x4 acc[8]) {
    int l15 = lane & 15, kg = lane >> 4;
    int rbase = row0 + wv * 16 + kg * 4;
#pragma unroll
    for (int rr = 0; rr < 4; ++rr) {
        ushort_t* dst = C + (size_t)(rbase + rr) * E_DIM + l15;
#pragma unroll
        for (int nf = 0; nf < 8; ++nf) dst[nf * 16] = f2bf(acc[nf][rr]);
    }
}

__device__ inline void epi_f32(float* C, int row0, int wv, int lane, f32x4 acc[8]) {
    int l15 = lane & 15, kg = lane >> 4;
    int rbase = row0 + wv * 16 + kg * 4;
#pragma unroll
    for (int rr = 0; rr < 4; ++rr) {
        float* dst = C + (size_t)(rbase + rr) * E_DIM + l15;
#pragma unroll
        for (int nf = 0; nf < 8; ++nf) dst[nf * 16] = acc[nf][rr];
    }
}

#define ZERO_ACC(a) do { _Pragma("unroll") for (int _i = 0; _i < 8; ++_i) \
    (a)[_i] = (f32x4){0.f, 0.f, 0.f, 0.f}; } while (0)

// ---------------------------------------------------------------------------
// K1: blocks [0, NB): nearest (L1 argmin, first-min tie-break)
//     blocks [NB, NB+64): fp32->bf16 n-major weight transpose
// ---------------------------------------------------------------------------
__global__ __launch_bounds__(256) void pre_kernel(
        const float* __restrict__ xc_off, const float* __restrict__ xc_on,
        const float* __restrict__ Wq, const float* __restrict__ Wk,
        const float* __restrict__ Wv, const float* __restrict__ Wo,
        ushort_t* __restrict__ WT, int* __restrict__ nearest, int U, int S, int B) {
    __shared__ __align__(16) char smraw[36928];
    const int NB = (U / 32) * B;
    int bid = blockIdx.x;
    int tid = threadIdx.x;
    if (bid >= NB) {
        int base = (bid - NB) * 1024 + tid;
#pragma unroll
        for (int j = 0; j < 4; ++j) {
            int idx = base + j * 256;
            int w = idx >> 14;
            int rem = idx & 16383;
            int k = rem >> 7, n = rem & 127;
            const float* src = (w == 0) ? Wq : (w == 1) ? Wk : (w == 2) ? Wv : Wo;
            WT[(size_t)w * 16384 + n * E_DIM + k] = f2bf(src[k * E_DIM + n]);
        }
        return;
    }
    float4* on = (float4*)smraw;                          // 32 KB
    float (*sh_d)[32] = (float(*)[32])(smraw + 32768);    // 2 KB
    int   (*sh_i)[32] = (int(*)[32])(smraw + 34816);      // 2 KB
    int tpb = U / 32;
    int b = bid / tpb;
    int xt = bid - b * tpb;
    const float4* onb = (const float4*)(xc_on + (size_t)b * S * 2);
    for (int i = tid; i < S / 2; i += 256) on[i] = onb[i];
    __syncthreads();
    int part = tid >> 4;
    int ug   = tid & 15;
    int u0 = xt * 32 + ug * 2;
    const float2* offb = (const float2*)(xc_off + (size_t)b * U * 2);
    float2 pA = offb[u0], pB = offb[u0 + 1];
    int h0 = part * (S / 32), h1 = h0 + (S / 32);
    float dA0 = FLT_MAX, dA1 = FLT_MAX, dB0 = FLT_MAX, dB1 = FLT_MAX;
    int iA0 = 0, iA1 = 0, iB0 = 0, iB1 = 0;
    for (int h = h0; h < h1; ++h) {
        float4 cc = on[h];
        int s = h * 2;
        float a0 = fabsf(pA.x - cc.x) + fabsf(pA.y - cc.y);
        float a1 = fabsf(pA.x - cc.z) + fabsf(pA.y - cc.w);
        float b0 = fabsf(pB.x - cc.x) + fabsf(pB.y - cc.y);
        float b1 = fabsf(pB.x - cc.z) + fabsf(pB.y - cc.w);
        if (a0 < dA0) { dA0 = a0; iA0 = s; }
        if (a1 < dA1) { dA1 = a1; iA1 = s + 1; }
        if (b0 < dB0) { dB0 = b0; iB0 = s; }
        if (b1 < dB1) { dB1 = b1; iB1 = s + 1; }
    }
    lexmin(dA0, iA0, dA1, iA1);
    lexmin(dB0, iB0, dB1, iB1);
    sh_d[part][ug * 2] = dA0;     sh_i[part][ug * 2] = iA0;
    sh_d[part][ug * 2 + 1] = dB0; sh_i[part][ug * 2 + 1] = iB0;
    __syncthreads();
    if (tid < 32) {
        float d = sh_d[0][tid]; int i = sh_i[0][tid];
#pragma unroll
        for (int pp = 1; pp < 16; ++pp) lexmin(d, i, sh_d[pp][tid], sh_i[pp][tid]);
        nearest[b * U + xt * 32 + tid] = i;
    }
}

// ---------------------------------------------------------------------------
// K2: blocks 0..B-1 = per-batch CSR build (offsets[b][s] = b*U + local prefix;
//     batches are independent since each contributes exactly U tokens).
//     blocks B.. = MFMA projection tiles (Q, then dual K/V).
// ---------------------------------------------------------------------------
__global__ __launch_bounds__(256) void proj_csr_kernel(
        const float* __restrict__ latents, const float* __restrict__ zc_off,
        const float* __restrict__ zc_on, const float* __restrict__ fake,
        const int* __restrict__ ignore, const ushort_t* __restrict__ WT,
        ushort_t* __restrict__ Qpre, ushort_t* __restrict__ Koff,
        ushort_t* __restrict__ Voff, ushort_t* __restrict__ Kon,
        ushort_t* __restrict__ Von,
        const int* __restrict__ nearest, int* __restrict__ offsets,
        int* __restrict__ tokens, int S, int U, int B) {
    __shared__ __align__(16) char sm[81920];   // 80 KB -> 2 blocks/CU
    const int BU = B * U;
    const int tid = threadIdx.x;

    if (blockIdx.x < (unsigned)B) {
        // ---- per-batch CSR: histogram -> scan -> fill, all in LDS ----
        int b = blockIdx.x;
        int* cnt  = (int*)sm;                  // S ints (16 KB)
        int* part = (int*)(sm + S * 4);        // 1 KB
        const int* nb = nearest + (size_t)b * U;
        for (int s = tid; s < S; s += 256) cnt[s] = 0;
        __syncthreads();
        for (int i = tid; i < U; i += 256) atomicAdd(&cnt[nb[i]], 1);
        __syncthreads();
        const int items = S / 256;             // 16
        int base = tid * items;
        int sum = 0;
        for (int i = 0; i < items; ++i) sum += cnt[base + i];
        part[tid] = sum;
        __syncthreads();
        for (int off = 1; off < 256; off <<= 1) {
            int v = (tid >= off) ? part[tid - off] : 0;
            __syncthreads();
            part[tid] += v;
            __syncthreads();
        }
        int run = b * U + ((tid == 0) ? 0 : part[tid - 1]);
        for (int i = 0; i < items; ++i) {
            int c = cnt[base + i];
            offsets[b * S + base + i] = run;
            cnt[base + i] = run;               // becomes the cursor
            run += c;
        }
        if (b == B - 1 && tid == 255) offsets[B * S] = B * U;
        __syncthreads();
        for (int i = tid; i < U; i += 256) {
            int pos = atomicAdd(&cnt[nb[i]], 1);
            tokens[pos] = i;
        }
        return;
    }

    // ---- projection tiles ----
    char* AsmB  = sm;            // 16 KB
    char* Wsm0B = sm + 16384;    // 32 KB
    char* Wsm1B = sm + 49152;    // 32 KB
    const int lane = tid & 63, wv = tid >> 6;
    const int nQ = S / 64, nOff = BU / 64;
    int t = blockIdx.x - B;
    const ushort_t* WqT = WT;
    const ushort_t* WkT = WT + 16384;
    const ushort_t* WvT = WT + 32768;

    if (t < nQ) {
        int row0 = t * 64;
        stage_A_f32(AsmB, latents + (size_t)row0 * E_DIM, nullptr, false, tid);
        stage_WT(Wsm0B, WqT, tid);
        __syncthreads();
        f32x4 acc[8]; ZERO_ACC(acc);
        mma_16x128(AsmB, Wsm0B, wv, lane, acc);
        epi_bf16(Qpre, row0, wv, lane, acc);
        return;
    }
    bool offg = (t < nQ + nOff);
    int tt = offg ? (t - nQ) : (t - nQ - nOff);
    int row0 = tt * 64;
    const float* A = offg ? zc_off : zc_on;
    bool ign = (!offg) && (*ignore != 0);
    ushort_t* C0 = offg ? Koff : Kon;
    ushort_t* C1 = offg ? Voff : Von;
    stage_A_f32(AsmB, A + (size_t)row0 * E_DIM, fake, ign, tid);
    stage_WT(Wsm0B, WkT, tid);
    stage_WT(Wsm1B, WvT, tid);
    __syncthreads();
    f32x4 acc0[8], acc1[8]; ZERO_ACC(acc0); ZERO_ACC(acc1);
    mma_16x128_dual(AsmB, Wsm0B, Wsm1B, wv, lane, acc0, acc1);
    epi_bf16(C0, row0, wv, lane, acc0);
    epi_bf16(C1, row0, wv, lane, acc1);
}

// ---------------------------------------------------------------------------
// K3: per-cell masked MHA (1 wave per cell, online softmax, bf16 K/V)
// ---------------------------------------------------------------------------
__global__ __launch_bounds__(256) void attn_kernel(
        const ushort_t* __restrict__ Qpre,
        const ushort_t* __restrict__ Koff, const ushort_t* __restrict__ Voff,
        const ushort_t* __restrict__ Kon, const ushort_t* __restrict__ Von,
        const int* __restrict__ offsets, const int* __restrict__ tokens,
        ushort_t* __restrict__ AO, int S, int U) {
    int wv = threadIdx.x >> 6;
    int lane = threadIdx.x & 63;
    int c = blockIdx.x * 4 + wv;
    int b = c / S;
    int cl = c - b * S;

    unsigned int qw = ((const unsigned int*)(Qpre + (size_t)cl * E_DIM))[lane];
    float q0 = bf2f(qw & 0xffffu) * 0.25f;   // 1/sqrt(dh) folded in
    float q1 = bf2f(qw >> 16) * 0.25f;

    unsigned int kw = ((const unsigned int*)(Kon + (size_t)c * E_DIM))[lane];
    float pp = q0 * bf2f(kw & 0xffffu) + q1 * bf2f(kw >> 16);
    pp += __shfl_xor(pp, 4, 8);
    pp += __shfl_xor(pp, 2, 8);
    pp += __shfl_xor(pp, 1, 8);
    unsigned int vw = ((const unsigned int*)(Von + (size_t)c * E_DIM))[lane];
    float mm = pp, ll = 1.f;
    float o0 = bf2f(vw & 0xffffu), o1 = bf2f(vw >> 16);

    int beg = offsets[c], end = offsets[c + 1];
    for (int t = beg; t < end; ++t) {
        int u = tokens[t];
        size_t rr = ((size_t)b * U + u) * E_DIM;
        unsigned int kw2 = ((const unsigned int*)(Koff + rr))[lane];
        unsigned int vw2 = ((const unsigned int*)(Voff + rr))[lane];
        float p2 = q0 * bf2f(kw2 & 0xffffu) + q1 * bf2f(kw2 >> 16);
        p2 += __shfl_xor(p2, 4, 8);
        p2 += __shfl_xor(p2, 2, 8);
        p2 += __shfl_xor(p2, 1, 8);
        float v0 = bf2f(vw2 & 0xffffu), v1 = bf2f(vw2 >> 16);
        float nm = fmaxf(mm, p2);
        float f = __expf(mm - nm), w = __expf(p2 - nm);
        ll = ll * f + w;
        o0 = o0 * f + w * v0;
        o1 = o1 * f + w * v1;
        mm = nm;
    }
    float inv = 1.f / ll;
    ((unsigned int*)(AO + (size_t)c * E_DIM))[lane] =
        (unsigned int)f2bf(o0 * inv) | ((unsigned int)f2bf(o1 * inv) << 16);
}

// ---------------------------------------------------------------------------
// K4: output projection AO(bf16) @ Wo -> out (fp32)
// ---------------------------------------------------------------------------
__global__ __launch_bounds__(256) void gemmO_kernel(
        const ushort_t* __restrict__ AO, const ushort_t* __restrict__ WoT,
        float* __restrict__ out, int BS) {
    __shared__ __align__(16) char sm[49152];
    char* AsmB = sm;
    char* WsmB = sm + 16384;
    int tid = threadIdx.x, lane = tid & 63, wv = tid >> 6;
    int row0 = blockIdx.x * 64;
    const char* abase = (const char*)(AO + (size_t)row0 * E_DIM);
#pragma unroll
    for (int i = 0; i < 4; ++i) {
        int gb = (tid + i * 256) * 16;
        int r = gb >> 8, cb = gb & 255;
        uint4 v = *(const uint4*)(abase + gb);
        *(uint4*)(AsmB + r * 256 + (cb ^ ((r & 7) << 4))) = v;
    }
    stage_WT(WsmB, WoT, tid);
    __syncthreads();
    f32x4 acc[8]; ZERO_ACC(acc);
    mma_16x128(AsmB, WsmB, wv, lane, acc);
    epi_f32(out, row0, wv, lane, acc);
}

// ---------------------------------------------------------------------------
extern "C" void kernel_launch(void* const* d_in, const int* in_sizes, int n_in,
                              void* d_out, int out_size, void* d_ws, size_t ws_size,
                              hipStream_t stream) {
    const float* xc_off  = (const float*)d_in[0];
    const float* xc_on   = (const float*)d_in[1];
    const float* zc_off  = (const float*)d_in[2];
    const float* zc_on   = (const float*)d_in[3];
    const float* latents = (const float*)d_in[4];
    const float* fake    = (const float*)d_in[5];
    const float* Wq      = (const float*)d_in[6];
    const float* Wk      = (const float*)d_in[7];
    const float* Wv      = (const float*)d_in[8];
    const float* Wo      = (const float*)d_in[9];
    const int*   ignore  = (const int*)d_in[10];

    const int E = in_sizes[5];              // 128
    const int S = in_sizes[4] / E;          // 4096
    const int B = in_sizes[1] / (S * 2);    // 4
    const int U = in_sizes[0] / (B * 2);    // 4096
    const int BS = B * S, BU = B * U;

    char* ws = (char*)d_ws;
    size_t off = 0;
    auto alloc = [&](size_t bytes) {
        size_t r = off;
        off += (bytes + 255) & ~(size_t)255;
        return r;
    };
    ushort_t* WT      = (ushort_t*)(ws + alloc((size_t)4 * E * E * 2));
    int*      nearest = (int*)(ws + alloc((size_t)BU * 4));
    int*      offsets = (int*)(ws + alloc((size_t)(BS + 1) * 4));
    int*      tokens  = (int*)(ws + alloc((size_t)BU * 4));
    ushort_t* Qpre    = (ushort_t*)(ws + alloc((size_t)S * E * 2));
    ushort_t* Koff    = (ushort_t*)(ws + alloc((size_t)BU * E * 2));
    ushort_t* Voff    = (ushort_t*)(ws + alloc((size_t)BU * E * 2));
    ushort_t* Kon     = (ushort_t*)(ws + alloc((size_t)BS * E * 2));
    ushort_t* Von     = (ushort_t*)(ws + alloc((size_t)BS * E * 2));
    ushort_t* AO      = (ushort_t*)(ws + alloc((size_t)BS * E * 2));

    const int NB = (U / 32) * B;            // 512 nearest blocks
    pre_kernel<<<NB + 64, 256, 0, stream>>>(xc_off, xc_on, Wq, Wk, Wv, Wo,
                                            WT, nearest, U, S, B);

    const int ntile = S / 64 + BU / 64 + BS / 64;   // 576
    proj_csr_kernel<<<ntile + B, 256, 0, stream>>>(latents, zc_off, zc_on, fake, ignore,
                                                   WT, Qpre, Koff, Voff, Kon, Von,
                                                   nearest, offsets, tokens, S, U, B);

    attn_kernel<<<BS / 4, 256, 0, stream>>>(Qpre, Koff, Voff, Kon, Von,
                                            offsets, tokens, AO, S, U);

    gemmO_kernel<<<BS / 64, 256, 0, stream>>>(AO, WT + 3 * E * E, (float*)d_out, BS);
}